// Round 1
// 1012.289 us; speedup vs baseline: 1.0256x; 1.0256x over previous
//
#include <hip/hip_runtime.h>
#include <math.h>

#define HID 64
#define G4 256
#define TSTEPS 256
#define BATCH 64
#define MTOT 16384
#define NVOCAB 8000

__device__ __forceinline__ float tanh_s(float x){
    float ax = fabsf(x);
    float e = __expf(-2.0f*ax);
    float t = (1.0f - e)/(1.0f + e);
    return x >= 0.f ? t : -t;
}

__global__ void bsum_k(const float* __restrict__ a, const float* __restrict__ b, float* __restrict__ o, int n){
    int i = blockIdx.x*256 + threadIdx.x;
    if (i < n) o[i] = a[i] + b[i];
}

// C[M][N] = A[M][KTOT] * B[N][KTOT]^T + bias[N]
// B is row-major [N][K] (PyTorch weight layout) -> no pre-transpose needed.
// 128x128 tile, 8x8 micro-tile/thread. Both LDS tiles K-major so all inner-loop
// reads are ds_read_b128 (4 per k per thread vs 10 mixed before).
template<int KTOT>
__global__ __launch_bounds__(256, 2) void gemm_bias_nt(
    const float* __restrict__ A, const float* __restrict__ B,
    const float* __restrict__ bias, float* __restrict__ C,
    int M, int N)
{
    __shared__ float As[64][132];   // [k][m], pad->conflict-free b128 reads
    __shared__ float Bs[64][132];   // [k][n]
    const int tid = threadIdx.x;
    const int tx = tid & 15;        // n quad group
    const int ty = tid >> 4;        // m group (0..15)
    const int m0 = blockIdx.y * 128;
    const int n0 = blockIdx.x * 128;

    float4 acc0[8], acc1[8];
    #pragma unroll
    for (int i = 0; i < 8; i++){
        acc0[i] = make_float4(0.f,0.f,0.f,0.f);
        acc1[i] = make_float4(0.f,0.f,0.f,0.f);
    }

    // staging mapping: row-fast = tid&15 (16 consecutive rows), k4 = (tid>>4)*4.
    // -> global: one 64B line per row per wave; LDS scalar stores 2-way aliased (free).
    const int rl = tid & 15;
    const int k4 = (tid >> 4) * 4;

    for (int k0 = 0; k0 < KTOT; k0 += 64){
        #pragma unroll
        for (int it = 0; it < 8; it++){
            int r = it*16 + rl;
            // A tile: 128m x 64k, transposed into As[k][m]
            float4 va = *(const float4*)(A + (size_t)(m0+r)*KTOT + k0 + k4);
            As[k4+0][r] = va.x; As[k4+1][r] = va.y;
            As[k4+2][r] = va.z; As[k4+3][r] = va.w;
            // B tile: 128n x 64k, transposed into Bs[k][n]
            float4 vb = make_float4(0.f,0.f,0.f,0.f);
            if (n0 + r < N)
                vb = *(const float4*)(B + (size_t)(n0+r)*KTOT + k0 + k4);
            Bs[k4+0][r] = vb.x; Bs[k4+1][r] = vb.y;
            Bs[k4+2][r] = vb.z; Bs[k4+3][r] = vb.w;
        }
        __syncthreads();

        #pragma unroll 8
        for (int k = 0; k < 64; k++){
            float4 a0 = *(const float4*)&As[k][ty*8];
            float4 a1 = *(const float4*)&As[k][ty*8 + 4];
            float4 b0 = *(const float4*)&Bs[k][tx*4];
            float4 b1 = *(const float4*)&Bs[k][64 + tx*4];
            float av[8] = {a0.x,a0.y,a0.z,a0.w,a1.x,a1.y,a1.z,a1.w};
            #pragma unroll
            for (int i = 0; i < 8; i++){
                acc0[i].x = fmaf(av[i], b0.x, acc0[i].x);
                acc0[i].y = fmaf(av[i], b0.y, acc0[i].y);
                acc0[i].z = fmaf(av[i], b0.z, acc0[i].z);
                acc0[i].w = fmaf(av[i], b0.w, acc0[i].w);
                acc1[i].x = fmaf(av[i], b1.x, acc1[i].x);
                acc1[i].y = fmaf(av[i], b1.y, acc1[i].y);
                acc1[i].z = fmaf(av[i], b1.z, acc1[i].z);
                acc1[i].w = fmaf(av[i], b1.w, acc1[i].w);
            }
        }
        __syncthreads();
    }

    const int v0a = n0 + tx*4;
    const int v0b = n0 + 64 + tx*4;
    float4 ba = make_float4(0.f,0.f,0.f,0.f);
    float4 bb = make_float4(0.f,0.f,0.f,0.f);
    if (v0a < N) ba = *(const float4*)(bias + v0a);
    if (v0b < N) bb = *(const float4*)(bias + v0b);
    #pragma unroll
    for (int i = 0; i < 8; i++){
        int m = m0 + ty*8 + i;
        float* crow = C + (size_t)m*N;
        if (v0a < N){
            float4 r;
            r.x = acc0[i].x + ba.x; r.y = acc0[i].y + ba.y;
            r.z = acc0[i].z + ba.z; r.w = acc0[i].w + ba.w;
            *(float4*)(crow + v0a) = r;
        }
        if (v0b < N){
            float4 r;
            r.x = acc1[i].x + bb.x; r.y = acc1[i].y + bb.y;
            r.z = acc1[i].z + bb.z; r.w = acc1[i].w + bb.w;
            *(float4*)(crow + v0b) = r;
        }
    }
}

// One block per batch element, 256 threads.
// Quad layout: lane -> (h-index j, gate g); gate exchange via quad shuffles.
// ONE barrier per step (step t reads hist[t], writes hist[t+1] -> no race).
// Full h history in LDS, coalesced bulk flush at the end.
__global__ __launch_bounds__(256) void lstm_recur(
    const float* __restrict__ XP, const float* __restrict__ Whh,
    float* __restrict__ Hout)
{
    const int b = blockIdx.x;
    const int tid = threadIdx.x;
    const int lane = tid & 63;
    const int wave = tid >> 6;
    const int g  = lane & 3;                 // 0:i 1:f 2:g 3:o
    const int j  = wave*16 + (lane >> 2);    // h index 0..63
    const int row = g*64 + j;                // Whh / gate row
    const bool gb0 = (g & 1) != 0;
    const bool gb1 = (g & 2) != 0;
    const bool is_g = (g == 2);

    __shared__ __align__(16) float hist[TSTEPS+1][HID];

    float4 w[16];
    {
        const float4* wr = (const float4*)(Whh + (size_t)row*HID);
        #pragma unroll
        for (int i = 0; i < 16; i++) w[i] = wr[i];
    }

    if (tid < HID) hist[0][tid] = 0.f;
    __syncthreads();

    const float* xprow = XP + (size_t)b*TSTEPS*G4 + row;
    float xn0 = xprow[0];
    float xn1 = xprow[G4];
    float c = 0.f;

    for (int t = 0; t < TSTEPS; t++){
        float a = xn0;
        xn0 = xn1;
        if (t + 2 < TSTEPS) xn1 = xprow[(size_t)(t+2)*G4];   // 2-deep prefetch

        const float4* hv = (const float4*)hist[t];
        float s0=0.f, s1=0.f, s2=0.f, s3=0.f;
        #pragma unroll
        for (int i = 0; i < 16; i += 4){
            float4 h0 = hv[i+0];
            float4 h1 = hv[i+1];
            float4 h2 = hv[i+2];
            float4 h3 = hv[i+3];
            s0 = fmaf(w[i+0].x,h0.x,s0); s0 = fmaf(w[i+0].y,h0.y,s0);
            s0 = fmaf(w[i+0].z,h0.z,s0); s0 = fmaf(w[i+0].w,h0.w,s0);
            s1 = fmaf(w[i+1].x,h1.x,s1); s1 = fmaf(w[i+1].y,h1.y,s1);
            s1 = fmaf(w[i+1].z,h1.z,s1); s1 = fmaf(w[i+1].w,h1.w,s1);
            s2 = fmaf(w[i+2].x,h2.x,s2); s2 = fmaf(w[i+2].y,h2.y,s2);
            s2 = fmaf(w[i+2].z,h2.z,s2); s2 = fmaf(w[i+2].w,h2.w,s2);
            s3 = fmaf(w[i+3].x,h3.x,s3); s3 = fmaf(w[i+3].y,h3.y,s3);
            s3 = fmaf(w[i+3].z,h3.z,s3); s3 = fmaf(w[i+3].w,h3.w,s3);
        }
        a += (s0+s1) + (s2+s3);

        // sigmoid for i,f,o; tanh for g via 2*sigmoid(2x)-1
        float aa = is_g ? 2.f*a : a;
        float sg = 1.f/(1.f + __expf(-aa));
        float act = is_g ? 2.f*sg - 1.f : sg;

        // quad all-gather: ak = gate value of (g ^ k)
        float a1v = __shfl_xor(act, 1, 64);
        float a2v = __shfl_xor(act, 2, 64);
        float a3v = __shfl_xor(act, 3, 64);
        // resolve bit0, then bit1 -> (i,f,g,o) in every lane
        float x0 = gb0 ? a1v : act;   // gate(2*b1)
        float x1 = gb0 ? act : a1v;   // gate(2*b1+1)
        float x2 = gb0 ? a3v : a2v;   // gate(2*(1-b1))
        float x3 = gb0 ? a2v : a3v;   // gate(2*(1-b1)+1)
        float ig = gb1 ? x2 : x0;
        float fg = gb1 ? x3 : x1;
        float gg = gb1 ? x0 : x2;
        float og = gb1 ? x1 : x3;

        c = fmaf(fg, c, ig*gg);       // replicated identically in all 4 quad lanes
        float hn = og * tanh_s(c);
        if (g == 0) hist[t+1][j] = hn;
        __syncthreads();
    }

    // coalesced bulk flush of h history (rows 1..256)
    const float4* h4 = (const float4*)&hist[1][0];
    float4* o4 = (float4*)(Hout + (size_t)b*TSTEPS*HID);
    #pragma unroll 4
    for (int i = tid; i < TSTEPS*HID/4; i += 256) o4[i] = h4[i];
}

extern "C" void kernel_launch(void* const* d_in, const int* in_sizes, int n_in,
                              void* d_out, int out_size, void* d_ws, size_t ws_size,
                              hipStream_t stream)
{
    const float* x    = (const float*)d_in[0];
    const float* Wih0 = (const float*)d_in[1];
    const float* Whh0 = (const float*)d_in[2];
    const float* bih0 = (const float*)d_in[3];
    const float* bhh0 = (const float*)d_in[4];
    const float* Wih1 = (const float*)d_in[5];
    const float* Whh1 = (const float*)d_in[6];
    const float* bih1 = (const float*)d_in[7];
    const float* bhh1 = (const float*)d_in[8];
    const float* Wl   = (const float*)d_in[9];
    const float* bl   = (const float*)d_in[10];
    float* out = (float*)d_out;

    float* ws  = (float*)d_ws;
    float* bs0 = ws;                  // 256
    float* bs1 = bs0 + 256;           // 256
    float* xp0 = bs1 + 256;           // [16384][256]
    float* xp1 = xp0 + 4194304;       // [16384][256]
    float* h1  = xp1 + 4194304;       // [16384][64]
    float* h2  = h1  + 1048576;       // [16384][64]

    bsum_k<<<1, 256, 0, stream>>>(bih0, bhh0, bs0, 256);
    bsum_k<<<1, 256, 0, stream>>>(bih1, bhh1, bs1, 256);

    // layer 0: xp0 = x @ Wih0^T + (bih0+bhh0)
    gemm_bias_nt<256><<<dim3(2,128), 256, 0, stream>>>(x, Wih0, bs0, xp0, MTOT, 256);
    lstm_recur<<<BATCH, 256, 0, stream>>>(xp0, Whh0, h1);

    // layer 1
    gemm_bias_nt<64><<<dim3(2,128), 256, 0, stream>>>(h1, Wih1, bs1, xp1, MTOT, 256);
    lstm_recur<<<BATCH, 256, 0, stream>>>(xp1, Whh1, h2);

    // vocab projection: out = h2 @ Wl^T + bl
    gemm_bias_nt<64><<<dim3(63,128), 256, 0, stream>>>(h2, Wl, bl, out, MTOT, NVOCAB);
}